// Round 3
// baseline (1388.800 us; speedup 1.0000x reference)
//
#include <hip/hip_runtime.h>
#include <hip/hip_bf16.h>
#include <math.h>
#include <stdint.h>

#define DEV static __device__ __forceinline__

typedef __attribute__((ext_vector_type(8))) short short8;
typedef __attribute__((ext_vector_type(8))) unsigned short ushort8;
typedef __attribute__((ext_vector_type(4))) float floatx4;

using bf16 = __hip_bfloat16;

constexpr int Bc = 2, Sc = 2048, Dc = 1024, Hc = 16, DHc = 64, Ec = 8, Fc = 4096;
constexpr int Tc = Bc * Sc;  // 4096 tokens

DEV floatx4 mfma_bf16(short8 a, short8 b, floatx4 c) {
  return __builtin_amdgcn_mfma_f32_16x16x32_bf16(a, b, c, 0, 0, 0);
}

DEV float gelu_tanh(float x) {
  float z = 0.7978845608028654f * (x + 0.044715f * x * x * x);
  z = fminf(fmaxf(z, -15.f), 15.f);
  float t = __expf(2.f * z);
  return 0.5f * x * (1.f + (t - 1.f) / (t + 1.f));
}

// async global -> LDS, 16B per lane. LDS dest must be wave-uniform base;
// HW writes lane i at base + i*16 (guide §5 / m97).
DEV void gl16(const void* g, void* l) {
  __builtin_amdgcn_global_load_lds(
      reinterpret_cast<const __attribute__((address_space(1))) void*>(
          reinterpret_cast<uintptr_t>(g)),
      reinterpret_cast<__attribute__((address_space(3))) void*>(
          reinterpret_cast<uintptr_t>(l)),
      16, 0, 0);
}

// ---------------------------------------------------------------------------
// Weight transpose+convert: W fp32 [K][N] -> Wt bf16 [N][K].
// ---------------------------------------------------------------------------
DEV void tr_tile(const float* __restrict__ W, bf16* __restrict__ Wt,
                 int K, int N, bf16 (*Ts)[72]) {
  const int n0 = blockIdx.x * 64, k0 = blockIdx.y * 64;
  const int tid = threadIdx.x;
#pragma unroll
  for (int it = 0; it < 4; it++) {
    int u = tid + it * 256;
    int r = u >> 4, c4 = (u & 15) << 2;
    floatx4 v = *(const floatx4*)(W + (size_t)(k0 + r) * N + n0 + c4);
#pragma unroll
    for (int j = 0; j < 4; j++) Ts[c4 + j][r] = __float2bfloat16(v[j]);
  }
  __syncthreads();
#pragma unroll
  for (int it = 0; it < 2; it++) {
    int u = tid + it * 256;
    int rn = u >> 3, kc = (u & 7) << 3;
    *(short8*)(Wt + (size_t)(n0 + rn) * K + k0 + kc) = *(const short8*)(&Ts[rn][kc]);
  }
}

__global__ __launch_bounds__(256) void k_wt(const float* __restrict__ W,
                                            bf16* __restrict__ Wt, int K, int N) {
  __shared__ __align__(16) bf16 Ts[64][72];
  const size_t mb = (size_t)blockIdx.z * K * N;
  tr_tile(W + mb, Wt + mb, K, N, Ts);
}

__global__ __launch_bounds__(256) void k_wt4(
    const float* __restrict__ a, const float* __restrict__ b,
    const float* __restrict__ c, const float* __restrict__ d,
    bf16* __restrict__ o) {
  __shared__ __align__(16) bf16 Ts[64][72];
  const int z = blockIdx.z;
  const float* W = z == 0 ? a : (z == 1 ? b : (z == 2 ? c : d));
  tr_tile(W, o + (size_t)z * Dc * Dc, Dc, Dc, Ts);
}

// ---------------------------------------------------------------------------
// GEMM core, m97 structure at BK=32: single-buffered 16 KB LDS so ~4-5
// blocks/CU stay resident (cross-block TLP does the latency hiding — m114).
// Per K-step: barrier; stage (4x gl16/thread); barrier; 8 ds_read_b128 +
// 16 MFMA. LDS bank-conflict fix (rule #21, both-sides-or-neither): linear
// LDS dest (gl16 requirement) + XOR-swizzled per-lane GLOBAL source +
// identical XOR on the ds_read address. For BK=32 (4 granules of 16B/row,
// 64B row stride) the involution is granule ^= (row>>1)&3, which puts each
// quad's 16 lanes on 8 bank-groups x 2 lanes = conflict-free.
// On the fragment read, row = base + l15 with base % 8 == 0, so the XOR
// reduces to (l15>>1)&3 — wave-uniform across mi/ni.
// MFMA 16x16x32_bf16: A[m=lane&15][k=quad*8+j], B[k=quad*8+j][n=lane&15],
// C col=lane&15 row=quad*4+r (verified layouts, unchanged).
// ---------------------------------------------------------------------------
DEV void gemm_core(bf16* As, bf16* Bs,
                   const bf16* __restrict__ A, int lda, int m0,
                   const bf16* __restrict__ Bt, int ldb, int n0,
                   int Kdim, floatx4 (&acc)[4][4]) {
  const int tid = threadIdx.x;
  const int lane = tid & 63;
  const int wave = tid >> 6;
  const int wm = wave & 1, wn = wave >> 1;
  const int l15 = lane & 15, quad = lane >> 4;

#pragma unroll
  for (int mi = 0; mi < 4; mi++)
#pragma unroll
    for (int ni = 0; ni < 4; ni++)
#pragma unroll
      for (int r = 0; r < 4; r++) acc[mi][ni][r] = 0.f;

  const int srow0 = tid >> 2;                 // staging row, +64 on it=1
  const int sg = tid & 3;                     // staging granule 0..3
  const int sw = ((quad ^ ((l15 >> 1) & 3)) << 3);  // read-side swizzle
  const int nK = Kdim >> 5;

  for (int kb = 0; kb < nK; kb++) {
    const int k0 = kb << 5;
    __syncthreads();  // LDS reuse fence (prev compute done)
#pragma unroll
    for (int it = 0; it < 2; it++) {
      const int row = srow0 + it * 64;
      const int sk = k0 + ((sg ^ ((row >> 1) & 3)) << 3);  // pre-swizzled src
      const int lbase = (it * 256 + wave * 64) * 8;        // wave-uniform
      gl16(A + (size_t)(m0 + row) * lda + sk, As + lbase);
      gl16(Bt + (size_t)(n0 + row) * ldb + sk, Bs + lbase);
    }
    __syncthreads();  // implicit vmcnt(0): publish staged tiles
    short8 af[4], bfr[4];
#pragma unroll
    for (int mi = 0; mi < 4; mi++)
      af[mi] = *(const short8*)(As + (wm * 64 + mi * 16 + l15) * 32 + sw);
#pragma unroll
    for (int ni = 0; ni < 4; ni++)
      bfr[ni] = *(const short8*)(Bs + (wn * 64 + ni * 16 + l15) * 32 + sw);
#pragma unroll
    for (int mi = 0; mi < 4; mi++)
#pragma unroll
      for (int ni = 0; ni < 4; ni++)
        acc[mi][ni] = mfma_bf16(af[mi], bfr[ni], acc[mi][ni]);
  }
}

#define GEMM_SHARED \
  __shared__ __align__(16) bf16 As[128 * 32]; \
  __shared__ __align__(16) bf16 Bs[128 * 32];
#define LANE_DECODE \
  const int tid = threadIdx.x; const int lane = tid & 63; const int wave = tid >> 6; \
  const int wm = wave & 1, wn = wave >> 1; const int l15 = lane & 15, quad = lane >> 4; \
  (void)tid; (void)lane;
// XCD-chunked bijective block swizzle (T1, m204): consecutive remapped
// blocks (same A-panel) share an XCD's L2. Requires nwg % 8 == 0 (all our
// grids: 8x32, 32x32). GX/GY are compile-time so %,/ are cheap.
#define XCD_SWZ(GX, GY) \
  int bx, by; { \
    constexpr int nwg = (GX) * (GY); \
    int flat = blockIdx.y * (GX) + blockIdx.x; \
    int wg = (flat & 7) * (nwg >> 3) + (flat >> 3); \
    bx = wg % (GX); by = wg / (GX); }

// --------------------------- RMSNorm (fp32 in, bf16 + optional fp32 out) ---
__global__ __launch_bounds__(256) void k_rms(const float* __restrict__ x,
                                             const float* __restrict__ w,
                                             bf16* __restrict__ out,
                                             float* __restrict__ outf) {
  __shared__ float red[4];
  const int tid = threadIdx.x, lane = tid & 63, wave = tid >> 6;
  const size_t base = (size_t)blockIdx.x * Dc + tid * 4;
  floatx4 v = *(const floatx4*)(x + base);
  float ss = v[0] * v[0] + v[1] * v[1] + v[2] * v[2] + v[3] * v[3];
#pragma unroll
  for (int off = 32; off >= 1; off >>= 1) ss += __shfl_xor(ss, off);
  if (lane == 0) red[wave] = ss;
  __syncthreads();
  float tot = red[0] + red[1] + red[2] + red[3];
  float rr = rsqrtf(tot * (1.f / Dc) + 1e-6f);
  floatx4 wv = *(const floatx4*)(w + tid * 4);
  floatx4 res;
#pragma unroll
  for (int j = 0; j < 4; j++) res[j] = v[j] * rr * wv[j];
#pragma unroll
  for (int j = 0; j < 4; j++) out[base + j] = __float2bfloat16(res[j]);
  if (outf) *(floatx4*)(outf + base) = res;
}

// ------------------------------ QKV GEMM -----------------------------------
__global__ __launch_bounds__(256, 4) void k_gemm_qkv(
    const bf16* __restrict__ xn, const bf16* __restrict__ wt,
    bf16* __restrict__ q, bf16* __restrict__ k, bf16* __restrict__ v) {
  GEMM_SHARED; LANE_DECODE;
  XCD_SWZ(Dc / 128, Tc / 128);
  const bf16* W = wt + (size_t)blockIdx.z * Dc * Dc;
  bf16* out = blockIdx.z == 0 ? q : (blockIdx.z == 1 ? k : v);
  const int m0 = by * 128, n0 = bx * 128;
  floatx4 acc[4][4];
  gemm_core(As, Bs, xn, Dc, m0, W, Dc, n0, Dc, acc);
#pragma unroll
  for (int mi = 0; mi < 4; mi++)
#pragma unroll
    for (int ni = 0; ni < 4; ni++)
#pragma unroll
      for (int r = 0; r < 4; r++) {
        int row = m0 + wm * 64 + mi * 16 + quad * 4 + r;  // token
        int col = n0 + wn * 64 + ni * 16 + l15;           // feature
        int b = row >> 11, s = row & 2047, h = col >> 6, dh = col & 63;
        out[((((size_t)b * Hc + h) * Sc + s) << 6) + dh] = __float2bfloat16(acc[mi][ni][r]);
      }
}

// ------------------------- output proj + residual --------------------------
__global__ __launch_bounds__(256, 4) void k_gemm_wo(
    const bf16* __restrict__ ctx, const bf16* __restrict__ wot,
    const float* __restrict__ x, float* __restrict__ x1) {
  GEMM_SHARED; LANE_DECODE;
  XCD_SWZ(Dc / 128, Tc / 128);
  const int m0 = by * 128, n0 = bx * 128;
  floatx4 acc[4][4];
  gemm_core(As, Bs, ctx, Dc, m0, wot, Dc, n0, Dc, acc);
#pragma unroll
  for (int mi = 0; mi < 4; mi++)
#pragma unroll
    for (int ni = 0; ni < 4; ni++)
#pragma unroll
      for (int r = 0; r < 4; r++) {
        int row = m0 + wm * 64 + mi * 16 + quad * 4 + r;
        int col = n0 + wn * 64 + ni * 16 + l15;
        size_t idx = (size_t)row * Dc + col;
        x1[idx] = acc[mi][ni][r] + x[idx];
      }
}

// ------------------------------ attention ----------------------------------
__global__ __launch_bounds__(256) void k_attn(
    const bf16* __restrict__ Q, const bf16* __restrict__ K,
    const bf16* __restrict__ V, bf16* __restrict__ ctx) {
  __shared__ __align__(16) bf16 Ks[32 * 72];
  __shared__ __align__(16) bf16 Vs[64 * 40];
  __shared__ __align__(16) bf16 Ps[4 * 16 * 40];
  const int tid = threadIdx.x, lane = tid & 63, wave = tid >> 6;
  const int l15 = lane & 15, quad = lane >> 4;
  const int bh = blockIdx.y;
  const size_t base = (size_t)bh * Sc * DHc;
  const bf16* Qb = Q + base; const bf16* Kb = K + base; const bf16* Vb = V + base;
  const int q0 = blockIdx.x * 64 + wave * 16;
  bf16* Pw = Ps + wave * (16 * 40);

  short8 aq[2];
#pragma unroll
  for (int kk2 = 0; kk2 < 2; kk2++)
    aq[kk2] = *(const short8*)(Qb + (size_t)(q0 + l15) * 64 + kk2 * 32 + quad * 8);

  float m_i[4], l_i[4];
  floatx4 o[4];
#pragma unroll
  for (int r = 0; r < 4; r++) { m_i[r] = -__builtin_inff(); l_i[r] = 0.f; }
#pragma unroll
  for (int n4 = 0; n4 < 4; n4++)
#pragma unroll
    for (int r = 0; r < 4; r++) o[n4][r] = 0.f;

  for (int kt = 0; kt < Sc / 32; kt++) {
    const int kb = kt * 32;
    __syncthreads();
    {  // K tile: 32 rows x 64 dh (row-major, stride 72)
      int row = tid >> 3, kc = (tid & 7) << 3;
      *(short8*)(Ks + row * 72 + kc) = *(const short8*)(Kb + (size_t)(kb + row) * 64 + kc);
    }
    if (tid < 128) {  // V tile transposed: Vs[dh][key], stride 40, swizzled
      int kp = tid >> 3, dg = tid & 7;
      ushort8 a0 = *(const ushort8*)(Vb + (size_t)(kb + 2 * kp) * 64 + dg * 8);
      ushort8 a1 = *(const ushort8*)(Vb + (size_t)(kb + 2 * kp + 1) * 64 + dg * 8);
#pragma unroll
      for (int j = 0; j < 8; j++) {
        int dh = dg * 8 + j;
        int elem = dh * 40 + ((((kp >> 2) ^ (dh >> 3)) & 3) << 3) + ((kp & 3) << 1);
        *(unsigned int*)(Vs + elem) = (unsigned int)a0[j] | ((unsigned int)a1[j] << 16);
      }
    }
    __syncthreads();
    floatx4 sc[2];
#pragma unroll
    for (int ni = 0; ni < 2; ni++) {
#pragma unroll
      for (int r = 0; r < 4; r++) sc[ni][r] = 0.f;
#pragma unroll
      for (int kk2 = 0; kk2 < 2; kk2++) {
        short8 bk = *(const short8*)(Ks + (ni * 16 + l15) * 72 + kk2 * 32 + quad * 8);
        sc[ni] = mfma_bf16(aq[kk2], bk, sc[ni]);
      }
    }
#pragma unroll
    for (int ni = 0; ni < 2; ni++)
#pragma unroll
      for (int r = 0; r < 4; r++) sc[ni][r] *= 0.125f;
    float rmax[4];
#pragma unroll
    for (int r = 0; r < 4; r++) rmax[r] = fmaxf(sc[0][r], sc[1][r]);
#pragma unroll
    for (int off = 1; off < 16; off <<= 1)
#pragma unroll
      for (int r = 0; r < 4; r++) rmax[r] = fmaxf(rmax[r], __shfl_xor(rmax[r], off));
    float alpha[4], rsum[4];
#pragma unroll
    for (int r = 0; r < 4; r++) {
      float nm = fmaxf(m_i[r], rmax[r]);
      alpha[r] = __expf(m_i[r] - nm);
      m_i[r] = nm;
    }
#pragma unroll
    for (int ni = 0; ni < 2; ni++)
#pragma unroll
      for (int r = 0; r < 4; r++) sc[ni][r] = __expf(sc[ni][r] - m_i[r]);
#pragma unroll
    for (int r = 0; r < 4; r++) rsum[r] = sc[0][r] + sc[1][r];
#pragma unroll
    for (int off = 1; off < 16; off <<= 1)
#pragma unroll
      for (int r = 0; r < 4; r++) rsum[r] += __shfl_xor(rsum[r], off);
#pragma unroll
    for (int r = 0; r < 4; r++) l_i[r] = l_i[r] * alpha[r] + rsum[r];
#pragma unroll
    for (int n4 = 0; n4 < 4; n4++)
#pragma unroll
      for (int r = 0; r < 4; r++) o[n4][r] *= alpha[r];
    // P (C layout) -> LDS -> A layout
#pragma unroll
    for (int ni = 0; ni < 2; ni++)
#pragma unroll
      for (int r = 0; r < 4; r++)
        Pw[(quad * 4 + r) * 40 + ni * 16 + l15] = __float2bfloat16(sc[ni][r]);
    __syncthreads();
    short8 ap = *(const short8*)(Pw + l15 * 40 + quad * 8);
#pragma unroll
    for (int n4 = 0; n4 < 4; n4++) {
      int dh = n4 * 16 + l15;
      short8 bv = *(const short8*)(Vs + dh * 40 + (((quad ^ (dh >> 3)) & 3) << 3));
      o[n4] = mfma_bf16(ap, bv, o[n4]);
    }
  }
  const int b = bh >> 4, h = bh & 15;
#pragma unroll
  for (int n4 = 0; n4 < 4; n4++)
#pragma unroll
    for (int r = 0; r < 4; r++) {
      int s = q0 + quad * 4 + r;
      int d = h * 64 + n4 * 16 + l15;
      ctx[(size_t)(b * Sc + s) * Dc + d] = __float2bfloat16(o[n4][r] / l_i[r]);
    }
}

// ------------------------------- router (pure fp32) ------------------------
__global__ __launch_bounds__(256) void k_router(
    const float* __restrict__ xn2f, const float* __restrict__ wr,
    int* __restrict__ topi, float* __restrict__ topw,
    int* __restrict__ counts, float* __restrict__ sum_probs,
    float* __restrict__ sum_z2) {
  __shared__ float sp[8]; __shared__ float sz[1]; __shared__ int scnt[8];
  const int tid = threadIdx.x, wave = tid >> 6, lane = tid & 63;
  if (tid < 8) { sp[tid] = 0.f; scnt[tid] = 0; }
  if (tid == 0) sz[0] = 0.f;
  __syncthreads();
  const int t = blockIdx.x * 4 + wave;
  float a[8];
#pragma unroll
  for (int e = 0; e < 8; e++) a[e] = 0.f;
  const float* xr = xn2f + (size_t)t * Dc;
#pragma unroll 4
  for (int i = 0; i < 16; i++) {
    int d = lane + i * 64;
    float xv = xr[d];
    floatx4 wa = *(const floatx4*)(wr + d * 8);
    floatx4 wb = *(const floatx4*)(wr + d * 8 + 4);
#pragma unroll
    for (int e = 0; e < 4; e++) a[e] += xv * wa[e];
#pragma unroll
    for (int e = 0; e < 4; e++) a[e + 4] += xv * wb[e];
  }
#pragma unroll
  for (int off = 1; off < 64; off <<= 1)
#pragma unroll
    for (int e = 0; e < 8; e++) a[e] += __shfl_xor(a[e], off);
  float mx = a[0];
#pragma unroll
  for (int e = 1; e < 8; e++) mx = fmaxf(mx, a[e]);
  float pr[8], sum = 0.f;
#pragma unroll
  for (int e = 0; e < 8; e++) { pr[e] = __expf(a[e] - mx); sum += pr[e]; }
  float inv = 1.f / sum;
#pragma unroll
  for (int e = 0; e < 8; e++) pr[e] *= inv;
  float lse = mx + logf(sum);
  int i0 = 0; float p0 = pr[0];
#pragma unroll
  for (int e = 1; e < 8; e++) if (pr[e] > p0) { p0 = pr[e]; i0 = e; }
  int i1 = -1; float p1 = -1.f;
#pragma unroll
  for (int e = 0; e < 8; e++) if (e != i0 && pr[e] > p1) { p1 = pr[e]; i1 = e; }
  float wsum = p0 + p1;
  if (lane == 0) {
    topi[2 * t] = i0; topi[2 * t + 1] = i1;
    topw[2 * t] = p0 / wsum; topw[2 * t + 1] = p1 / wsum;
    atomicAdd(&scnt[i0], 1); atomicAdd(&scnt[i1], 1);
#pragma unroll
    for (int e = 0; e < 8; e++) atomicAdd(&sp[e], pr[e]);
    atomicAdd(&sz[0], lse * lse);
  }
  __syncthreads();
  if (tid < 8) { atomicAdd(&counts[tid], scnt[tid]); atomicAdd(&sum_probs[tid], sp[tid]); }
  if (tid == 0) atomicAdd(sum_z2, sz[0]);
}

// offsets + router loss (single thread)
__global__ void k_meta(const int* __restrict__ counts, int* __restrict__ offs,
                       const float* __restrict__ sum_probs,
                       const float* __restrict__ sum_z2, float* __restrict__ loss_out) {
  float aux = 0.f;
  offs[0] = 0;
  for (int e = 0; e < 8; e++) {
    offs[e + 1] = offs[e] + counts[e];
    aux += ((float)counts[e] / Tc) * (sum_probs[e] / Tc);
  }
  float loss = (float)Ec * aux * 0.5f + 0.001f * (sum_z2[0] / Tc);
  loss_out[0] = loss;
}

// gather tokens into per-expert segments; record row slots for combine
__global__ __launch_bounds__(256) void k_gather(
    const bf16* __restrict__ xn2, const int* __restrict__ topi,
    const int* __restrict__ offs, int* __restrict__ cursors,
    int* __restrict__ rowpos, bf16* __restrict__ Ag) {
  const int tid = threadIdx.x, wave = tid >> 6, lane = tid & 63;
  const int t = blockIdx.x * 4 + wave;
  const int i0 = topi[2 * t], i1 = topi[2 * t + 1];
  int r0 = 0, r1 = 0;
  if (lane == 0) {
    r0 = atomicAdd(&cursors[i0], 1);
    r1 = atomicAdd(&cursors[i1], 1);
    rowpos[2 * t] = r0; rowpos[2 * t + 1] = r1;
  }
  r0 = __shfl(r0, 0); r1 = __shfl(r1, 0);
  const short8* src = (const short8*)(xn2 + (size_t)t * Dc);
  short8 c0 = src[lane], c1 = src[lane + 64];
  short8* d0 = (short8*)(Ag + (size_t)(offs[i0] + r0) * Dc);
  short8* d1 = (short8*)(Ag + (size_t)(offs[i1] + r1) * Dc);
  d0[lane] = c0; d0[lane + 64] = c1;
  d1[lane] = c0; d1[lane + 64] = c1;
}

// ------------------------------ expert FFN ---------------------------------
__global__ __launch_bounds__(256, 4) void k_ffn1(
    const bf16* __restrict__ Ag, const bf16* __restrict__ w1t,
    bf16* __restrict__ Hb, const int* __restrict__ offs) {
  const int e = blockIdx.z;
  const int cnt = offs[e + 1] - offs[e];
  XCD_SWZ(Fc / 128, Tc / 128);
  const int m0 = by * 128;
  if (m0 >= cnt) return;
  GEMM_SHARED; LANE_DECODE;
  const int n0 = bx * 128;
  const bf16* A = Ag + (size_t)offs[e] * Dc;
  const bf16* W = w1t + (size_t)e * Dc * Fc;  // [Fc][Dc]
  bf16* Hp = Hb + (size_t)offs[e] * Fc;
  floatx4 acc[4][4];
  gemm_core(As, Bs, A, Dc, m0, W, Dc, n0, Dc, acc);
#pragma unroll
  for (int mi = 0; mi < 4; mi++)
#pragma unroll
    for (int ni = 0; ni < 4; ni++)
#pragma unroll
      for (int r = 0; r < 4; r++) {
        int row = m0 + wm * 64 + mi * 16 + quad * 4 + r;
        int col = n0 + wn * 64 + ni * 16 + l15;
        if (row < cnt)
          Hp[(size_t)row * Fc + col] = __float2bfloat16(gelu_tanh(acc[mi][ni][r]));
      }
}

__global__ __launch_bounds__(256, 4) void k_ffn2(
    const bf16* __restrict__ Hb, const bf16* __restrict__ w2t,
    float* __restrict__ Ob, const int* __restrict__ offs) {
  const int e = blockIdx.z;
  const int cnt = offs[e + 1] - offs[e];
  XCD_SWZ(Dc / 128, Tc / 128);
  const int m0 = by * 128;
  if (m0 >= cnt) return;
  GEMM_SHARED; LANE_DECODE;
  const int n0 = bx * 128;
  const bf16* A = Hb + (size_t)offs[e] * Fc;
  const bf16* W = w2t + (size_t)e * Fc * Dc;  // [Dc][Fc]
  float* Op = Ob + (size_t)offs[e] * Dc;
  floatx4 acc[4][4];
  gemm_core(As, Bs, A, Fc, m0, W, Fc, n0, Fc, acc);
#pragma unroll
  for (int mi = 0; mi < 4; mi++)
#pragma unroll
    for (int ni = 0; ni < 4; ni++)
#pragma unroll
      for (int r = 0; r < 4; r++) {
        int row = m0 + wm * 64 + mi * 16 + quad * 4 + r;
        int col = n0 + wn * 64 + ni * 16 + l15;
        if (row < cnt) Op[(size_t)row * Dc + col] = acc[mi][ni][r];
      }
}

// ------------------------------- combine -----------------------------------
__global__ __launch_bounds__(256) void k_combine(
    const float* __restrict__ x1, const float* __restrict__ Ob,
    const int* __restrict__ topi, const float* __restrict__ topw,
    const int* __restrict__ rowpos, const int* __restrict__ offs,
    float* __restrict__ out) {
  const int t = blockIdx.x, tid = threadIdx.x;
  const int i0 = topi[2 * t], i1 = topi[2 * t + 1];
  const float w0 = topw[2 * t], w1 = topw[2 * t + 1];
  const float* o0 = Ob + (size_t)(offs[i0] + rowpos[2 * t]) * Dc;
  const float* o1 = Ob + (size_t)(offs[i1] + rowpos[2 * t + 1]) * Dc;
  const float* xr = x1 + (size_t)t * Dc;
  floatx4 a = *(const floatx4*)(xr + tid * 4);
  floatx4 b = *(const floatx4*)(o0 + tid * 4);
  floatx4 c = *(const floatx4*)(o1 + tid * 4);
  floatx4 res;
#pragma unroll
  for (int j = 0; j < 4; j++) res[j] = a[j] + w0 * b[j] + w1 * c[j];
  *(floatx4*)(out + (size_t)t * Dc + tid * 4) = res;
}

// ---------------------------------------------------------------------------
extern "C" void kernel_launch(void* const* d_in, const int* in_sizes, int n_in,
                              void* d_out, int out_size, void* d_ws, size_t ws_size,
                              hipStream_t stream) {
  (void)in_sizes; (void)n_in; (void)out_size; (void)ws_size;
  const float* x    = (const float*)d_in[0];
  const float* ln1w = (const float*)d_in[1];
  const float* ln2w = (const float*)d_in[2];
  const float* wq   = (const float*)d_in[3];
  const float* wk   = (const float*)d_in[4];
  const float* wv   = (const float*)d_in[5];
  const float* wo   = (const float*)d_in[6];
  const float* wr   = (const float*)d_in[7];
  const float* w1   = (const float*)d_in[8];
  const float* w2   = (const float*)d_in[9];
  float* out = (float*)d_out;

  char* p = (char*)d_ws;
  auto take = [&](size_t bytes) {
    char* r = p; p += (bytes + 255) & ~(size_t)255; return r;
  };
  bf16*  xn   = (bf16*)take((size_t)Tc * Dc * 2);
  bf16*  qb   = (bf16*)take((size_t)Tc * Dc * 2);
  bf16*  kb   = (bf16*)take((size_t)Tc * Dc * 2);
  bf16*  vb   = (bf16*)take((size_t)Tc * Dc * 2);
  bf16*  ctx  = (bf16*)take((size_t)Tc * Dc * 2);
  float* x1   = (float*)take((size_t)Tc * Dc * 4);
  bf16*  xn2  = (bf16*)take((size_t)Tc * Dc * 2);
  float* xn2f = (float*)take((size_t)Tc * Dc * 4);
  bf16*  Ag   = (bf16*)take((size_t)2 * Tc * Dc * 2);
  bf16*  Hb   = (bf16*)take((size_t)2 * Tc * Fc * 2);
  float* Ob   = (float*)take((size_t)2 * Tc * Dc * 4);
  bf16*  wtqkvo = (bf16*)take((size_t)4 * Dc * Dc * 2);           // q,k,v,o transposed bf16
  bf16*  wtbig  = (bf16*)take((size_t)Ec * (size_t)Dc * Fc * 2);  // shared w1t, then w2t
  int*   counts    = (int*)take(512);      // [0:8) counts, then cursors, sums
  int*   cursors   = counts + 8;
  float* sum_probs = (float*)(counts + 16);
  float* sum_z2    = sum_probs + 8;
  int*   offs      = (int*)take(256);
  int*   topi      = (int*)take((size_t)2 * Tc * 4);
  float* topw      = (float*)take((size_t)2 * Tc * 4);
  int*   rowpos    = (int*)take((size_t)2 * Tc * 4);

  hipMemsetAsync(counts, 0, 512, stream);

  // weight conversion (transpose fp32 [K][N] -> bf16 [N][K])
  k_wt4<<<dim3(Dc / 64, Dc / 64, 4), 256, 0, stream>>>(wq, wk, wv, wo, wtqkvo);
  k_wt<<<dim3(Fc / 64, Dc / 64, Ec), 256, 0, stream>>>(w1, wtbig, Dc, Fc);

  k_rms<<<Tc, 256, 0, stream>>>(x, ln1w, xn, nullptr);
  k_gemm_qkv<<<dim3(Dc / 128, Tc / 128, 3), 256, 0, stream>>>(xn, wtqkvo, qb, kb, vb);
  k_attn<<<dim3(Sc / 64, Bc * Hc), 256, 0, stream>>>(qb, kb, vb, ctx);
  k_gemm_wo<<<dim3(Dc / 128, Tc / 128), 256, 0, stream>>>(ctx, wtqkvo + (size_t)3 * Dc * Dc, x, x1);
  k_rms<<<Tc, 256, 0, stream>>>(x1, ln2w, xn2, xn2f);
  k_router<<<Tc / 4, 256, 0, stream>>>(xn2f, wr, topi, topw, counts, sum_probs, sum_z2);
  k_meta<<<1, 1, 0, stream>>>(counts, offs, sum_probs, sum_z2, out + (size_t)Tc * Dc);
  k_gather<<<Tc / 4, 256, 0, stream>>>(xn2, topi, offs, cursors, rowpos, Ag);
  k_ffn1<<<dim3(Fc / 128, Tc / 128, Ec), 256, 0, stream>>>(Ag, wtbig, Hb, offs);
  // w2 conversion reuses wtbig (stream-ordered after ffn1)
  k_wt<<<dim3(Dc / 64, Fc / 64, Ec), 256, 0, stream>>>(w2, wtbig, Fc, Dc);
  k_ffn2<<<dim3(Dc / 128, Tc / 128, Ec), 256, 0, stream>>>(Hb, wtbig, Ob, offs);
  k_combine<<<Tc, 256, 0, stream>>>(x1, Ob, topi, topw, rowpos, offs, out);
}

// Round 4
// 982.569 us; speedup vs baseline: 1.4134x; 1.4134x over previous
//
#include <hip/hip_runtime.h>
#include <hip/hip_bf16.h>
#include <math.h>
#include <stdint.h>

#define DEV static __device__ __forceinline__

typedef __attribute__((ext_vector_type(8))) short short8;
typedef __attribute__((ext_vector_type(8))) unsigned short ushort8;
typedef __attribute__((ext_vector_type(4))) float floatx4;

using bf16 = __hip_bfloat16;

constexpr int Bc = 2, Sc = 2048, Dc = 1024, Hc = 16, DHc = 64, Ec = 8, Fc = 4096;
constexpr int Tc = Bc * Sc;  // 4096 tokens

DEV floatx4 mfma_bf16(short8 a, short8 b, floatx4 c) {
  return __builtin_amdgcn_mfma_f32_16x16x32_bf16(a, b, c, 0, 0, 0);
}

DEV float gelu_tanh(float x) {
  float z = 0.7978845608028654f * (x + 0.044715f * x * x * x);
  z = fminf(fmaxf(z, -15.f), 15.f);
  float t = __expf(2.f * z);
  return 0.5f * x * (1.f + (t - 1.f) / (t + 1.f));
}

// async global -> LDS, 16B per lane. LDS dest must be wave-uniform base;
// HW writes lane i at base + i*16 (guide §5 / m97).
DEV void gl16(const void* g, void* l) {
  __builtin_amdgcn_global_load_lds(
      reinterpret_cast<const __attribute__((address_space(1))) void*>(
          reinterpret_cast<uintptr_t>(g)),
      reinterpret_cast<__attribute__((address_space(3))) void*>(
          reinterpret_cast<uintptr_t>(l)),
      16, 0, 0);
}

// ---------------------------------------------------------------------------
// Weight transpose+convert: W fp32 [K][N] -> Wt bf16 [N][K].
// ---------------------------------------------------------------------------
DEV void tr_tile(const float* __restrict__ W, bf16* __restrict__ Wt,
                 int K, int N, bf16 (*Ts)[72]) {
  const int n0 = blockIdx.x * 64, k0 = blockIdx.y * 64;
  const int tid = threadIdx.x;
#pragma unroll
  for (int it = 0; it < 4; it++) {
    int u = tid + it * 256;
    int r = u >> 4, c4 = (u & 15) << 2;
    floatx4 v = *(const floatx4*)(W + (size_t)(k0 + r) * N + n0 + c4);
#pragma unroll
    for (int j = 0; j < 4; j++) Ts[c4 + j][r] = __float2bfloat16(v[j]);
  }
  __syncthreads();
#pragma unroll
  for (int it = 0; it < 2; it++) {
    int u = tid + it * 256;
    int rn = u >> 3, kc = (u & 7) << 3;
    *(short8*)(Wt + (size_t)(n0 + rn) * K + k0 + kc) = *(const short8*)(&Ts[rn][kc]);
  }
}

__global__ __launch_bounds__(256) void k_wt(const float* __restrict__ W,
                                            bf16* __restrict__ Wt, int K, int N) {
  __shared__ __align__(16) bf16 Ts[64][72];
  const size_t mb = (size_t)blockIdx.z * K * N;
  tr_tile(W + mb, Wt + mb, K, N, Ts);
}

__global__ __launch_bounds__(256) void k_wt4(
    const float* __restrict__ a, const float* __restrict__ b,
    const float* __restrict__ c, const float* __restrict__ d,
    bf16* __restrict__ o) {
  __shared__ __align__(16) bf16 Ts[64][72];
  const int z = blockIdx.z;
  const float* W = z == 0 ? a : (z == 1 ? b : (z == 2 ? c : d));
  tr_tile(W, o + (size_t)z * Dc * Dc, Dc, Dc, Ts);
}

// ---------------------------------------------------------------------------
// GEMM core, m97 structure at BK=32: single-buffered 16 KB LDS so many
// blocks/CU stay resident (cross-block TLP does the latency hiding — m114).
// Per K-step: barrier; stage (4x gl16/thread); barrier; 8 ds_read_b128 +
// 16 MFMA. LDS bank-conflict fix (rule #21, both-sides-or-neither): linear
// LDS dest (gl16 requirement) + XOR-swizzled per-lane GLOBAL source +
// identical XOR on the ds_read address. For BK=32 the involution is
// granule ^= (row>>1)&3 — conflict-free (verified: SQ_LDS_BANK_CONFLICT=0,
// round 3). Local MfmaUtil of this core measured ~29% (round-3 counters
// rescaled to the 2 XCDs that were actually working).
// MFMA 16x16x32_bf16: A[m=lane&15][k=quad*8+j], B[k=quad*8+j][n=lane&15],
// C col=lane&15 row=quad*4+r (verified layouts, unchanged).
// ---------------------------------------------------------------------------
DEV void gemm_core(bf16* As, bf16* Bs,
                   const bf16* __restrict__ A, int lda, int m0,
                   const bf16* __restrict__ Bt, int ldb, int n0,
                   int Kdim, floatx4 (&acc)[4][4]) {
  const int tid = threadIdx.x;
  const int lane = tid & 63;
  const int wave = tid >> 6;
  const int wm = wave & 1, wn = wave >> 1;
  const int l15 = lane & 15, quad = lane >> 4;

#pragma unroll
  for (int mi = 0; mi < 4; mi++)
#pragma unroll
    for (int ni = 0; ni < 4; ni++)
#pragma unroll
      for (int r = 0; r < 4; r++) acc[mi][ni][r] = 0.f;

  const int srow0 = tid >> 2;                 // staging row, +64 on it=1
  const int sg = tid & 3;                     // staging granule 0..3
  const int sw = ((quad ^ ((l15 >> 1) & 3)) << 3);  // read-side swizzle
  const int nK = Kdim >> 5;

  for (int kb = 0; kb < nK; kb++) {
    const int k0 = kb << 5;
    __syncthreads();  // LDS reuse fence (prev compute done)
#pragma unroll
    for (int it = 0; it < 2; it++) {
      const int row = srow0 + it * 64;
      const int sk = k0 + ((sg ^ ((row >> 1) & 3)) << 3);  // pre-swizzled src
      const int lbase = (it * 256 + wave * 64) * 8;        // wave-uniform
      gl16(A + (size_t)(m0 + row) * lda + sk, As + lbase);
      gl16(Bt + (size_t)(n0 + row) * ldb + sk, Bs + lbase);
    }
    __syncthreads();  // implicit vmcnt(0): publish staged tiles
    short8 af[4], bfr[4];
#pragma unroll
    for (int mi = 0; mi < 4; mi++)
      af[mi] = *(const short8*)(As + (wm * 64 + mi * 16 + l15) * 32 + sw);
#pragma unroll
    for (int ni = 0; ni < 4; ni++)
      bfr[ni] = *(const short8*)(Bs + (wn * 64 + ni * 16 + l15) * 32 + sw);
#pragma unroll
    for (int mi = 0; mi < 4; mi++)
#pragma unroll
      for (int ni = 0; ni < 4; ni++)
        acc[mi][ni] = mfma_bf16(af[mi], bfr[ni], acc[mi][ni]);
  }
}

#define GEMM_SHARED \
  __shared__ __align__(16) bf16 As[128 * 32]; \
  __shared__ __align__(16) bf16 Bs[128 * 32];
#define LANE_DECODE \
  const int tid = threadIdx.x; const int lane = tid & 63; const int wave = tid >> 6; \
  const int wm = wave & 1, wn = wave >> 1; const int l15 = lane & 15, quad = lane >> 4; \
  (void)tid; (void)lane;
// XCD-chunked bijective block swizzle (T1, m204). ONLY for kernels where
// every block does work: with early-exit grids (FFN: by*128 >= cnt returns)
// this mapping concentrates all VALID blocks onto XCDs {0,1} — measured
// round 2/3: 4x slowdown, chip-wide occupancy 10%. FFN kernels use the
// natural mapping (xcd = bx%8, which spreads valid rows evenly).
#define XCD_SWZ(GX, GY) \
  int bx, by; { \
    constexpr int nwg = (GX) * (GY); \
    int flat = blockIdx.y * (GX) + blockIdx.x; \
    int wg = (flat & 7) * (nwg >> 3) + (flat >> 3); \
    bx = wg % (GX); by = wg / (GX); }

// --------------------------- RMSNorm (fp32 in, bf16 + optional fp32 out) ---
__global__ __launch_bounds__(256) void k_rms(const float* __restrict__ x,
                                             const float* __restrict__ w,
                                             bf16* __restrict__ out,
                                             float* __restrict__ outf) {
  __shared__ float red[4];
  const int tid = threadIdx.x, lane = tid & 63, wave = tid >> 6;
  const size_t base = (size_t)blockIdx.x * Dc + tid * 4;
  floatx4 v = *(const floatx4*)(x + base);
  float ss = v[0] * v[0] + v[1] * v[1] + v[2] * v[2] + v[3] * v[3];
#pragma unroll
  for (int off = 32; off >= 1; off >>= 1) ss += __shfl_xor(ss, off);
  if (lane == 0) red[wave] = ss;
  __syncthreads();
  float tot = red[0] + red[1] + red[2] + red[3];
  float rr = rsqrtf(tot * (1.f / Dc) + 1e-6f);
  floatx4 wv = *(const floatx4*)(w + tid * 4);
  floatx4 res;
#pragma unroll
  for (int j = 0; j < 4; j++) res[j] = v[j] * rr * wv[j];
#pragma unroll
  for (int j = 0; j < 4; j++) out[base + j] = __float2bfloat16(res[j]);
  if (outf) *(floatx4*)(outf + base) = res;
}

// ------------------------------ QKV GEMM -----------------------------------
__global__ __launch_bounds__(256, 4) void k_gemm_qkv(
    const bf16* __restrict__ xn, const bf16* __restrict__ wt,
    bf16* __restrict__ q, bf16* __restrict__ k, bf16* __restrict__ v) {
  GEMM_SHARED; LANE_DECODE;
  XCD_SWZ(Dc / 128, Tc / 128);
  const bf16* W = wt + (size_t)blockIdx.z * Dc * Dc;
  bf16* out = blockIdx.z == 0 ? q : (blockIdx.z == 1 ? k : v);
  const int m0 = by * 128, n0 = bx * 128;
  floatx4 acc[4][4];
  gemm_core(As, Bs, xn, Dc, m0, W, Dc, n0, Dc, acc);
#pragma unroll
  for (int mi = 0; mi < 4; mi++)
#pragma unroll
    for (int ni = 0; ni < 4; ni++)
#pragma unroll
      for (int r = 0; r < 4; r++) {
        int row = m0 + wm * 64 + mi * 16 + quad * 4 + r;  // token
        int col = n0 + wn * 64 + ni * 16 + l15;           // feature
        int b = row >> 11, s = row & 2047, h = col >> 6, dh = col & 63;
        out[((((size_t)b * Hc + h) * Sc + s) << 6) + dh] = __float2bfloat16(acc[mi][ni][r]);
      }
}

// ------------------------- output proj + residual --------------------------
__global__ __launch_bounds__(256, 4) void k_gemm_wo(
    const bf16* __restrict__ ctx, const bf16* __restrict__ wot,
    const float* __restrict__ x, float* __restrict__ x1) {
  GEMM_SHARED; LANE_DECODE;
  XCD_SWZ(Dc / 128, Tc / 128);
  const int m0 = by * 128, n0 = bx * 128;
  floatx4 acc[4][4];
  gemm_core(As, Bs, ctx, Dc, m0, wot, Dc, n0, Dc, acc);
#pragma unroll
  for (int mi = 0; mi < 4; mi++)
#pragma unroll
    for (int ni = 0; ni < 4; ni++)
#pragma unroll
      for (int r = 0; r < 4; r++) {
        int row = m0 + wm * 64 + mi * 16 + quad * 4 + r;
        int col = n0 + wn * 64 + ni * 16 + l15;
        size_t idx = (size_t)row * Dc + col;
        x1[idx] = acc[mi][ni][r] + x[idx];
      }
}

// ------------------------------ attention ----------------------------------
__global__ __launch_bounds__(256) void k_attn(
    const bf16* __restrict__ Q, const bf16* __restrict__ K,
    const bf16* __restrict__ V, bf16* __restrict__ ctx) {
  __shared__ __align__(16) bf16 Ks[32 * 72];
  __shared__ __align__(16) bf16 Vs[64 * 40];
  __shared__ __align__(16) bf16 Ps[4 * 16 * 40];
  const int tid = threadIdx.x, lane = tid & 63, wave = tid >> 6;
  const int l15 = lane & 15, quad = lane >> 4;
  const int bh = blockIdx.y;
  const size_t base = (size_t)bh * Sc * DHc;
  const bf16* Qb = Q + base; const bf16* Kb = K + base; const bf16* Vb = V + base;
  const int q0 = blockIdx.x * 64 + wave * 16;
  bf16* Pw = Ps + wave * (16 * 40);

  short8 aq[2];
#pragma unroll
  for (int kk2 = 0; kk2 < 2; kk2++)
    aq[kk2] = *(const short8*)(Qb + (size_t)(q0 + l15) * 64 + kk2 * 32 + quad * 8);

  float m_i[4], l_i[4];
  floatx4 o[4];
#pragma unroll
  for (int r = 0; r < 4; r++) { m_i[r] = -__builtin_inff(); l_i[r] = 0.f; }
#pragma unroll
  for (int n4 = 0; n4 < 4; n4++)
#pragma unroll
    for (int r = 0; r < 4; r++) o[n4][r] = 0.f;

  for (int kt = 0; kt < Sc / 32; kt++) {
    const int kb = kt * 32;
    __syncthreads();
    {  // K tile: 32 rows x 64 dh (row-major, stride 72)
      int row = tid >> 3, kc = (tid & 7) << 3;
      *(short8*)(Ks + row * 72 + kc) = *(const short8*)(Kb + (size_t)(kb + row) * 64 + kc);
    }
    if (tid < 128) {  // V tile transposed: Vs[dh][key], stride 40, swizzled
      int kp = tid >> 3, dg = tid & 7;
      ushort8 a0 = *(const ushort8*)(Vb + (size_t)(kb + 2 * kp) * 64 + dg * 8);
      ushort8 a1 = *(const ushort8*)(Vb + (size_t)(kb + 2 * kp + 1) * 64 + dg * 8);
#pragma unroll
      for (int j = 0; j < 8; j++) {
        int dh = dg * 8 + j;
        int elem = dh * 40 + ((((kp >> 2) ^ (dh >> 3)) & 3) << 3) + ((kp & 3) << 1);
        *(unsigned int*)(Vs + elem) = (unsigned int)a0[j] | ((unsigned int)a1[j] << 16);
      }
    }
    __syncthreads();
    floatx4 sc[2];
#pragma unroll
    for (int ni = 0; ni < 2; ni++) {
#pragma unroll
      for (int r = 0; r < 4; r++) sc[ni][r] = 0.f;
#pragma unroll
      for (int kk2 = 0; kk2 < 2; kk2++) {
        short8 bk = *(const short8*)(Ks + (ni * 16 + l15) * 72 + kk2 * 32 + quad * 8);
        sc[ni] = mfma_bf16(aq[kk2], bk, sc[ni]);
      }
    }
#pragma unroll
    for (int ni = 0; ni < 2; ni++)
#pragma unroll
      for (int r = 0; r < 4; r++) sc[ni][r] *= 0.125f;
    float rmax[4];
#pragma unroll
    for (int r = 0; r < 4; r++) rmax[r] = fmaxf(sc[0][r], sc[1][r]);
#pragma unroll
    for (int off = 1; off < 16; off <<= 1)
#pragma unroll
      for (int r = 0; r < 4; r++) rmax[r] = fmaxf(rmax[r], __shfl_xor(rmax[r], off));
    float alpha[4], rsum[4];
#pragma unroll
    for (int r = 0; r < 4; r++) {
      float nm = fmaxf(m_i[r], rmax[r]);
      alpha[r] = __expf(m_i[r] - nm);
      m_i[r] = nm;
    }
#pragma unroll
    for (int ni = 0; ni < 2; ni++)
#pragma unroll
      for (int r = 0; r < 4; r++) sc[ni][r] = __expf(sc[ni][r] - m_i[r]);
#pragma unroll
    for (int r = 0; r < 4; r++) rsum[r] = sc[0][r] + sc[1][r];
#pragma unroll
    for (int off = 1; off < 16; off <<= 1)
#pragma unroll
      for (int r = 0; r < 4; r++) rsum[r] += __shfl_xor(rsum[r], off);
#pragma unroll
    for (int r = 0; r < 4; r++) l_i[r] = l_i[r] * alpha[r] + rsum[r];
#pragma unroll
    for (int n4 = 0; n4 < 4; n4++)
#pragma unroll
      for (int r = 0; r < 4; r++) o[n4][r] *= alpha[r];
    // P (C layout) -> LDS -> A layout
#pragma unroll
    for (int ni = 0; ni < 2; ni++)
#pragma unroll
      for (int r = 0; r < 4; r++)
        Pw[(quad * 4 + r) * 40 + ni * 16 + l15] = __float2bfloat16(sc[ni][r]);
    __syncthreads();
    short8 ap = *(const short8*)(Pw + l15 * 40 + quad * 8);
#pragma unroll
    for (int n4 = 0; n4 < 4; n4++) {
      int dh = n4 * 16 + l15;
      short8 bv = *(const short8*)(Vs + dh * 40 + (((quad ^ (dh >> 3)) & 3) << 3));
      o[n4] = mfma_bf16(ap, bv, o[n4]);
    }
  }
  const int b = bh >> 4, h = bh & 15;
#pragma unroll
  for (int n4 = 0; n4 < 4; n4++)
#pragma unroll
    for (int r = 0; r < 4; r++) {
      int s = q0 + quad * 4 + r;
      int d = h * 64 + n4 * 16 + l15;
      ctx[(size_t)(b * Sc + s) * Dc + d] = __float2bfloat16(o[n4][r] / l_i[r]);
    }
}

// ------------------------------- router (pure fp32) ------------------------
__global__ __launch_bounds__(256) void k_router(
    const float* __restrict__ xn2f, const float* __restrict__ wr,
    int* __restrict__ topi, float* __restrict__ topw,
    int* __restrict__ counts, float* __restrict__ sum_probs,
    float* __restrict__ sum_z2) {
  __shared__ float sp[8]; __shared__ float sz[1]; __shared__ int scnt[8];
  const int tid = threadIdx.x, wave = tid >> 6, lane = tid & 63;
  if (tid < 8) { sp[tid] = 0.f; scnt[tid] = 0; }
  if (tid == 0) sz[0] = 0.f;
  __syncthreads();
  const int t = blockIdx.x * 4 + wave;
  float a[8];
#pragma unroll
  for (int e = 0; e < 8; e++) a[e] = 0.f;
  const float* xr = xn2f + (size_t)t * Dc;
#pragma unroll 4
  for (int i = 0; i < 16; i++) {
    int d = lane + i * 64;
    float xv = xr[d];
    floatx4 wa = *(const floatx4*)(wr + d * 8);
    floatx4 wb = *(const floatx4*)(wr + d * 8 + 4);
#pragma unroll
    for (int e = 0; e < 4; e++) a[e] += xv * wa[e];
#pragma unroll
    for (int e = 0; e < 4; e++) a[e + 4] += xv * wb[e];
  }
#pragma unroll
  for (int off = 1; off < 64; off <<= 1)
#pragma unroll
    for (int e = 0; e < 8; e++) a[e] += __shfl_xor(a[e], off);
  float mx = a[0];
#pragma unroll
  for (int e = 1; e < 8; e++) mx = fmaxf(mx, a[e]);
  float pr[8], sum = 0.f;
#pragma unroll
  for (int e = 0; e < 8; e++) { pr[e] = __expf(a[e] - mx); sum += pr[e]; }
  float inv = 1.f / sum;
#pragma unroll
  for (int e = 0; e < 8; e++) pr[e] *= inv;
  float lse = mx + logf(sum);
  int i0 = 0; float p0 = pr[0];
#pragma unroll
  for (int e = 1; e < 8; e++) if (pr[e] > p0) { p0 = pr[e]; i0 = e; }
  int i1 = -1; float p1 = -1.f;
#pragma unroll
  for (int e = 0; e < 8; e++) if (e != i0 && pr[e] > p1) { p1 = pr[e]; i1 = e; }
  float wsum = p0 + p1;
  if (lane == 0) {
    topi[2 * t] = i0; topi[2 * t + 1] = i1;
    topw[2 * t] = p0 / wsum; topw[2 * t + 1] = p1 / wsum;
    atomicAdd(&scnt[i0], 1); atomicAdd(&scnt[i1], 1);
#pragma unroll
    for (int e = 0; e < 8; e++) atomicAdd(&sp[e], pr[e]);
    atomicAdd(&sz[0], lse * lse);
  }
  __syncthreads();
  if (tid < 8) { atomicAdd(&counts[tid], scnt[tid]); atomicAdd(&sum_probs[tid], sp[tid]); }
  if (tid == 0) atomicAdd(sum_z2, sz[0]);
}

// offsets + router loss (single thread)
__global__ void k_meta(const int* __restrict__ counts, int* __restrict__ offs,
                       const float* __restrict__ sum_probs,
                       const float* __restrict__ sum_z2, float* __restrict__ loss_out) {
  float aux = 0.f;
  offs[0] = 0;
  for (int e = 0; e < 8; e++) {
    offs[e + 1] = offs[e] + counts[e];
    aux += ((float)counts[e] / Tc) * (sum_probs[e] / Tc);
  }
  float loss = (float)Ec * aux * 0.5f + 0.001f * (sum_z2[0] / Tc);
  loss_out[0] = loss;
}

// gather tokens into per-expert segments; record row slots for combine
__global__ __launch_bounds__(256) void k_gather(
    const bf16* __restrict__ xn2, const int* __restrict__ topi,
    const int* __restrict__ offs, int* __restrict__ cursors,
    int* __restrict__ rowpos, bf16* __restrict__ Ag) {
  const int tid = threadIdx.x, wave = tid >> 6, lane = tid & 63;
  const int t = blockIdx.x * 4 + wave;
  const int i0 = topi[2 * t], i1 = topi[2 * t + 1];
  int r0 = 0, r1 = 0;
  if (lane == 0) {
    r0 = atomicAdd(&cursors[i0], 1);
    r1 = atomicAdd(&cursors[i1], 1);
    rowpos[2 * t] = r0; rowpos[2 * t + 1] = r1;
  }
  r0 = __shfl(r0, 0); r1 = __shfl(r1, 0);
  const short8* src = (const short8*)(xn2 + (size_t)t * Dc);
  short8 c0 = src[lane], c1 = src[lane + 64];
  short8* d0 = (short8*)(Ag + (size_t)(offs[i0] + r0) * Dc);
  short8* d1 = (short8*)(Ag + (size_t)(offs[i1] + r1) * Dc);
  d0[lane] = c0; d0[lane + 64] = c1;
  d1[lane] = c0; d1[lane + 64] = c1;
}

// ------------------------------ expert FFN ---------------------------------
// NOTE: natural block mapping (no XCD swizzle). With early-exit on
// by*128 >= cnt, the XCD-chunked swizzle concentrated all valid blocks on
// XCDs {0,1} (rounds 2/3: 4x slowdown). Natural order assigns xcd = bx%8,
// which distributes valid rows across all XCDs.
__global__ __launch_bounds__(256, 4) void k_ffn1(
    const bf16* __restrict__ Ag, const bf16* __restrict__ w1t,
    bf16* __restrict__ Hb, const int* __restrict__ offs) {
  const int e = blockIdx.z;
  const int cnt = offs[e + 1] - offs[e];
  const int m0 = blockIdx.y * 128;
  if (m0 >= cnt) return;
  GEMM_SHARED; LANE_DECODE;
  const int n0 = blockIdx.x * 128;
  const bf16* A = Ag + (size_t)offs[e] * Dc;
  const bf16* W = w1t + (size_t)e * Dc * Fc;  // [Fc][Dc]
  bf16* Hp = Hb + (size_t)offs[e] * Fc;
  floatx4 acc[4][4];
  gemm_core(As, Bs, A, Dc, m0, W, Dc, n0, Dc, acc);
#pragma unroll
  for (int mi = 0; mi < 4; mi++)
#pragma unroll
    for (int ni = 0; ni < 4; ni++)
#pragma unroll
      for (int r = 0; r < 4; r++) {
        int row = m0 + wm * 64 + mi * 16 + quad * 4 + r;
        int col = n0 + wn * 64 + ni * 16 + l15;
        if (row < cnt)
          Hp[(size_t)row * Fc + col] = __float2bfloat16(gelu_tanh(acc[mi][ni][r]));
      }
}

__global__ __launch_bounds__(256, 4) void k_ffn2(
    const bf16* __restrict__ Hb, const bf16* __restrict__ w2t,
    float* __restrict__ Ob, const int* __restrict__ offs) {
  const int e = blockIdx.z;
  const int cnt = offs[e + 1] - offs[e];
  const int m0 = blockIdx.y * 128;
  if (m0 >= cnt) return;
  GEMM_SHARED; LANE_DECODE;
  const int n0 = blockIdx.x * 128;
  const bf16* A = Hb + (size_t)offs[e] * Fc;
  const bf16* W = w2t + (size_t)e * Fc * Dc;  // [Dc][Fc]
  float* Op = Ob + (size_t)offs[e] * Dc;
  floatx4 acc[4][4];
  gemm_core(As, Bs, A, Fc, m0, W, Fc, n0, Fc, acc);
#pragma unroll
  for (int mi = 0; mi < 4; mi++)
#pragma unroll
    for (int ni = 0; ni < 4; ni++)
#pragma unroll
      for (int r = 0; r < 4; r++) {
        int row = m0 + wm * 64 + mi * 16 + quad * 4 + r;
        int col = n0 + wn * 64 + ni * 16 + l15;
        if (row < cnt) Op[(size_t)row * Dc + col] = acc[mi][ni][r];
      }
}

// ------------------------------- combine -----------------------------------
__global__ __launch_bounds__(256) void k_combine(
    const float* __restrict__ x1, const float* __restrict__ Ob,
    const int* __restrict__ topi, const float* __restrict__ topw,
    const int* __restrict__ rowpos, const int* __restrict__ offs,
    float* __restrict__ out) {
  const int t = blockIdx.x, tid = threadIdx.x;
  const int i0 = topi[2 * t], i1 = topi[2 * t + 1];
  const float w0 = topw[2 * t], w1 = topw[2 * t + 1];
  const float* o0 = Ob + (size_t)(offs[i0] + rowpos[2 * t]) * Dc;
  const float* o1 = Ob + (size_t)(offs[i1] + rowpos[2 * t + 1]) * Dc;
  const float* xr = x1 + (size_t)t * Dc;
  floatx4 a = *(const floatx4*)(xr + tid * 4);
  floatx4 b = *(const floatx4*)(o0 + tid * 4);
  floatx4 c = *(const floatx4*)(o1 + tid * 4);
  floatx4 res;
#pragma unroll
  for (int j = 0; j < 4; j++) res[j] = a[j] + w0 * b[j] + w1 * c[j];
  *(floatx4*)(out + (size_t)t * Dc + tid * 4) = res;
}

// ---------------------------------------------------------------------------
extern "C" void kernel_launch(void* const* d_in, const int* in_sizes, int n_in,
                              void* d_out, int out_size, void* d_ws, size_t ws_size,
                              hipStream_t stream) {
  (void)in_sizes; (void)n_in; (void)out_size; (void)ws_size;
  const float* x    = (const float*)d_in[0];
  const float* ln1w = (const float*)d_in[1];
  const float* ln2w = (const float*)d_in[2];
  const float* wq   = (const float*)d_in[3];
  const float* wk   = (const float*)d_in[4];
  const float* wv   = (const float*)d_in[5];
  const float* wo   = (const float*)d_in[6];
  const float* wr   = (const float*)d_in[7];
  const float* w1   = (const float*)d_in[8];
  const float* w2   = (const float*)d_in[9];
  float* out = (float*)d_out;

  char* p = (char*)d_ws;
  auto take = [&](size_t bytes) {
    char* r = p; p += (bytes + 255) & ~(size_t)255; return r;
  };
  bf16*  xn   = (bf16*)take((size_t)Tc * Dc * 2);
  bf16*  qb   = (bf16*)take((size_t)Tc * Dc * 2);
  bf16*  kb   = (bf16*)take((size_t)Tc * Dc * 2);
  bf16*  vb   = (bf16*)take((size_t)Tc * Dc * 2);
  bf16*  ctx  = (bf16*)take((size_t)Tc * Dc * 2);
  float* x1   = (float*)take((size_t)Tc * Dc * 4);
  bf16*  xn2  = (bf16*)take((size_t)Tc * Dc * 2);
  float* xn2f = (float*)take((size_t)Tc * Dc * 4);
  bf16*  Ag   = (bf16*)take((size_t)2 * Tc * Dc * 2);
  bf16*  Hb   = (bf16*)take((size_t)2 * Tc * Fc * 2);
  float* Ob   = (float*)take((size_t)2 * Tc * Dc * 4);
  bf16*  wtqkvo = (bf16*)take((size_t)4 * Dc * Dc * 2);           // q,k,v,o transposed bf16
  bf16*  wtbig  = (bf16*)take((size_t)Ec * (size_t)Dc * Fc * 2);  // shared w1t, then w2t
  int*   counts    = (int*)take(512);      // [0:8) counts, then cursors, sums
  int*   cursors   = counts + 8;
  float* sum_probs = (float*)(counts + 16);
  float* sum_z2    = sum_probs + 8;
  int*   offs      = (int*)take(256);
  int*   topi      = (int*)take((size_t)2 * Tc * 4);
  float* topw      = (float*)take((size_t)2 * Tc * 4);
  int*   rowpos    = (int*)take((size_t)2 * Tc * 4);

  hipMemsetAsync(counts, 0, 512, stream);

  // weight conversion (transpose fp32 [K][N] -> bf16 [N][K])
  k_wt4<<<dim3(Dc / 64, Dc / 64, 4), 256, 0, stream>>>(wq, wk, wv, wo, wtqkvo);
  k_wt<<<dim3(Fc / 64, Dc / 64, Ec), 256, 0, stream>>>(w1, wtbig, Dc, Fc);

  k_rms<<<Tc, 256, 0, stream>>>(x, ln1w, xn, nullptr);
  k_gemm_qkv<<<dim3(Dc / 128, Tc / 128, 3), 256, 0, stream>>>(xn, wtqkvo, qb, kb, vb);
  k_attn<<<dim3(Sc / 64, Bc * Hc), 256, 0, stream>>>(qb, kb, vb, ctx);
  k_gemm_wo<<<dim3(Dc / 128, Tc / 128), 256, 0, stream>>>(ctx, wtqkvo + (size_t)3 * Dc * Dc, x, x1);
  k_rms<<<Tc, 256, 0, stream>>>(x1, ln2w, xn2, xn2f);
  k_router<<<Tc / 4, 256, 0, stream>>>(xn2f, wr, topi, topw, counts, sum_probs, sum_z2);
  k_meta<<<1, 1, 0, stream>>>(counts, offs, sum_probs, sum_z2, out + (size_t)Tc * Dc);
  k_gather<<<Tc / 4, 256, 0, stream>>>(xn2, topi, offs, cursors, rowpos, Ag);
  k_ffn1<<<dim3(Fc / 128, Tc / 128, Ec), 256, 0, stream>>>(Ag, wtbig, Hb, offs);
  // w2 conversion reuses wtbig (stream-ordered after ffn1)
  k_wt<<<dim3(Dc / 64, Fc / 64, Ec), 256, 0, stream>>>(w2, wtbig, Fc, Dc);
  k_ffn2<<<dim3(Dc / 128, Tc / 128, Ec), 256, 0, stream>>>(Hb, wtbig, Ob, offs);
  k_combine<<<Tc, 256, 0, stream>>>(x1, Ob, topi, topw, rowpos, offs, out);
}

// Round 5
// 930.939 us; speedup vs baseline: 1.4918x; 1.0555x over previous
//
#include <hip/hip_runtime.h>
#include <hip/hip_bf16.h>
#include <math.h>
#include <stdint.h>

#define DEV static __device__ __forceinline__

typedef __attribute__((ext_vector_type(8))) short short8;
typedef __attribute__((ext_vector_type(8))) unsigned short ushort8;
typedef __attribute__((ext_vector_type(4))) float floatx4;

using bf16 = __hip_bfloat16;

constexpr int Bc = 2, Sc = 2048, Dc = 1024, Hc = 16, DHc = 64, Ec = 8, Fc = 4096;
constexpr int Tc = Bc * Sc;  // 4096 tokens

DEV floatx4 mfma_bf16(short8 a, short8 b, floatx4 c) {
  return __builtin_amdgcn_mfma_f32_16x16x32_bf16(a, b, c, 0, 0, 0);
}

DEV float gelu_tanh(float x) {
  float z = 0.7978845608028654f * (x + 0.044715f * x * x * x);
  z = fminf(fmaxf(z, -15.f), 15.f);
  float t = __expf(2.f * z);
  return 0.5f * x * (1.f + (t - 1.f) / (t + 1.f));
}

// async global -> LDS, 16B per lane. LDS dest must be wave-uniform base;
// HW writes lane i at base + i*16 (guide §5 / m97).
DEV void gl16(const void* g, void* l) {
  __builtin_amdgcn_global_load_lds(
      reinterpret_cast<const __attribute__((address_space(1))) void*>(
          reinterpret_cast<uintptr_t>(g)),
      reinterpret_cast<__attribute__((address_space(3))) void*>(
          reinterpret_cast<uintptr_t>(l)),
      16, 0, 0);
}

// ---------------------------------------------------------------------------
// Weight transpose+convert: W fp32 [K][N] -> Wt bf16 [N][K].
// ---------------------------------------------------------------------------
DEV void tr_tile(const float* __restrict__ W, bf16* __restrict__ Wt,
                 int K, int N, bf16 (*Ts)[72]) {
  const int n0 = blockIdx.x * 64, k0 = blockIdx.y * 64;
  const int tid = threadIdx.x;
#pragma unroll
  for (int it = 0; it < 4; it++) {
    int u = tid + it * 256;
    int r = u >> 4, c4 = (u & 15) << 2;
    floatx4 v = *(const floatx4*)(W + (size_t)(k0 + r) * N + n0 + c4);
#pragma unroll
    for (int j = 0; j < 4; j++) Ts[c4 + j][r] = __float2bfloat16(v[j]);
  }
  __syncthreads();
#pragma unroll
  for (int it = 0; it < 2; it++) {
    int u = tid + it * 256;
    int rn = u >> 3, kc = (u & 7) << 3;
    *(short8*)(Wt + (size_t)(n0 + rn) * K + k0 + kc) = *(const short8*)(&Ts[rn][kc]);
  }
}

__global__ __launch_bounds__(256) void k_wt(const float* __restrict__ W,
                                            bf16* __restrict__ Wt, int K, int N) {
  __shared__ __align__(16) bf16 Ts[64][72];
  const size_t mb = (size_t)blockIdx.z * K * N;
  tr_tile(W + mb, Wt + mb, K, N, Ts);
}

__global__ __launch_bounds__(256) void k_wt4(
    const float* __restrict__ a, const float* __restrict__ b,
    const float* __restrict__ c, const float* __restrict__ d,
    bf16* __restrict__ o) {
  __shared__ __align__(16) bf16 Ts[64][72];
  const int z = blockIdx.z;
  const float* W = z == 0 ? a : (z == 1 ? b : (z == 2 ? c : d));
  tr_tile(W, o + (size_t)z * Dc * Dc, Dc, Dc, Ts);
}

// ---------------------------------------------------------------------------
// GEMM core, m97 structure at BK=32 (proven round 3/4: conflict-free,
// ~690 TF local). Single-buffered 16 KB LDS; cross-block TLP hides latency.
// ---------------------------------------------------------------------------
DEV void gemm_core(bf16* As, bf16* Bs,
                   const bf16* __restrict__ A, int lda, int m0,
                   const bf16* __restrict__ Bt, int ldb, int n0,
                   int Kdim, floatx4 (&acc)[4][4]) {
  const int tid = threadIdx.x;
  const int lane = tid & 63;
  const int wave = tid >> 6;
  const int wm = wave & 1, wn = wave >> 1;
  const int l15 = lane & 15, quad = lane >> 4;

#pragma unroll
  for (int mi = 0; mi < 4; mi++)
#pragma unroll
    for (int ni = 0; ni < 4; ni++)
#pragma unroll
      for (int r = 0; r < 4; r++) acc[mi][ni][r] = 0.f;

  const int srow0 = tid >> 2;                 // staging row, +64 on it=1
  const int sg = tid & 3;                     // staging granule 0..3
  const int sw = ((quad ^ ((l15 >> 1) & 3)) << 3);  // read-side swizzle
  const int nK = Kdim >> 5;

  for (int kb = 0; kb < nK; kb++) {
    const int k0 = kb << 5;
    __syncthreads();  // LDS reuse fence (prev compute done)
#pragma unroll
    for (int it = 0; it < 2; it++) {
      const int row = srow0 + it * 64;
      const int sk = k0 + ((sg ^ ((row >> 1) & 3)) << 3);  // pre-swizzled src
      const int lbase = (it * 256 + wave * 64) * 8;        // wave-uniform
      gl16(A + (size_t)(m0 + row) * lda + sk, As + lbase);
      gl16(Bt + (size_t)(n0 + row) * ldb + sk, Bs + lbase);
    }
    __syncthreads();  // implicit vmcnt(0): publish staged tiles
    short8 af[4], bfr[4];
#pragma unroll
    for (int mi = 0; mi < 4; mi++)
      af[mi] = *(const short8*)(As + (wm * 64 + mi * 16 + l15) * 32 + sw);
#pragma unroll
    for (int ni = 0; ni < 4; ni++)
      bfr[ni] = *(const short8*)(Bs + (wn * 64 + ni * 16 + l15) * 32 + sw);
#pragma unroll
    for (int mi = 0; mi < 4; mi++)
#pragma unroll
      for (int ni = 0; ni < 4; ni++)
        acc[mi][ni] = mfma_bf16(af[mi], bfr[ni], acc[mi][ni]);
  }
}

#define GEMM_SHARED \
  __shared__ __align__(16) bf16 As[128 * 32]; \
  __shared__ __align__(16) bf16 Bs[128 * 32];
#define LANE_DECODE \
  const int tid = threadIdx.x; const int lane = tid & 63; const int wave = tid >> 6; \
  const int wm = wave & 1, wn = wave >> 1; const int l15 = lane & 15, quad = lane >> 4; \
  (void)tid; (void)lane;
// XCD-chunked bijective block swizzle (T1, m204). ONLY for kernels where
// every block does work (rounds 2/3: with early-exit FFN grids it
// concentrated all valid blocks on XCDs {0,1} — 4x slowdown).
#define XCD_SWZ(GX, GY) \
  int bx, by; { \
    constexpr int nwg = (GX) * (GY); \
    int flat = blockIdx.y * (GX) + blockIdx.x; \
    int wg = (flat & 7) * (nwg >> 3) + (flat >> 3); \
    bx = wg % (GX); by = wg / (GX); }

// --------------------------- RMSNorm (fp32 in, bf16 + optional fp32 out) ---
__global__ __launch_bounds__(256) void k_rms(const float* __restrict__ x,
                                             const float* __restrict__ w,
                                             bf16* __restrict__ out,
                                             float* __restrict__ outf) {
  __shared__ float red[4];
  const int tid = threadIdx.x, lane = tid & 63, wave = tid >> 6;
  const size_t base = (size_t)blockIdx.x * Dc + tid * 4;
  floatx4 v = *(const floatx4*)(x + base);
  float ss = v[0] * v[0] + v[1] * v[1] + v[2] * v[2] + v[3] * v[3];
#pragma unroll
  for (int off = 32; off >= 1; off >>= 1) ss += __shfl_xor(ss, off);
  if (lane == 0) red[wave] = ss;
  __syncthreads();
  float tot = red[0] + red[1] + red[2] + red[3];
  float rr = rsqrtf(tot * (1.f / Dc) + 1e-6f);
  floatx4 wv = *(const floatx4*)(w + tid * 4);
  floatx4 res;
#pragma unroll
  for (int j = 0; j < 4; j++) res[j] = v[j] * rr * wv[j];
#pragma unroll
  for (int j = 0; j < 4; j++) out[base + j] = __float2bfloat16(res[j]);
  if (outf) *(floatx4*)(outf + base) = res;
}

// ------------------------------ QKV GEMM -----------------------------------
// Q output is pre-scaled by 1/sqrt(Dh) = 0.125 (exact power of 2 — lossless
// in bf16), so k_attn skips the per-score scale.
__global__ __launch_bounds__(256, 4) void k_gemm_qkv(
    const bf16* __restrict__ xn, const bf16* __restrict__ wt,
    bf16* __restrict__ q, bf16* __restrict__ k, bf16* __restrict__ v) {
  GEMM_SHARED; LANE_DECODE;
  XCD_SWZ(Dc / 128, Tc / 128);
  const bf16* W = wt + (size_t)blockIdx.z * Dc * Dc;
  bf16* out = blockIdx.z == 0 ? q : (blockIdx.z == 1 ? k : v);
  const float qsc = (blockIdx.z == 0) ? 0.125f : 1.0f;
  const int m0 = by * 128, n0 = bx * 128;
  floatx4 acc[4][4];
  gemm_core(As, Bs, xn, Dc, m0, W, Dc, n0, Dc, acc);
#pragma unroll
  for (int mi = 0; mi < 4; mi++)
#pragma unroll
    for (int ni = 0; ni < 4; ni++)
#pragma unroll
      for (int r = 0; r < 4; r++) {
        int row = m0 + wm * 64 + mi * 16 + quad * 4 + r;  // token
        int col = n0 + wn * 64 + ni * 16 + l15;           // feature
        int b = row >> 11, s = row & 2047, h = col >> 6, dh = col & 63;
        out[((((size_t)b * Hc + h) * Sc + s) << 6) + dh] =
            __float2bfloat16(acc[mi][ni][r] * qsc);
      }
}

// ------------------------- output proj + residual --------------------------
__global__ __launch_bounds__(256, 4) void k_gemm_wo(
    const bf16* __restrict__ ctx, const bf16* __restrict__ wot,
    const float* __restrict__ x, float* __restrict__ x1) {
  GEMM_SHARED; LANE_DECODE;
  XCD_SWZ(Dc / 128, Tc / 128);
  const int m0 = by * 128, n0 = bx * 128;
  floatx4 acc[4][4];
  gemm_core(As, Bs, ctx, Dc, m0, wot, Dc, n0, Dc, acc);
#pragma unroll
  for (int mi = 0; mi < 4; mi++)
#pragma unroll
    for (int ni = 0; ni < 4; ni++)
#pragma unroll
      for (int r = 0; r < 4; r++) {
        int row = m0 + wm * 64 + mi * 16 + quad * 4 + r;
        int col = n0 + wn * 64 + ni * 16 + l15;
        size_t idx = (size_t)row * Dc + col;
        x1[idx] = acc[mi][ni][r] + x[idx];
      }
}

// ------------------------------ attention ----------------------------------
// KVBLK=64 flash tiles (was 32): halves barriers / shuffle-rounds / rescale
// passes per key. K tile: linear [64][64] LDS via gl16 with both-sides
// granule XOR g^=(row&7) (rule #21). V tile transposed [dh][key], stride 72,
// 3-bit granule XOR sg=(key>>3)^(dh>>3): staging writes 2-way (free), PV
// reads 8 lanes/4-bank window (optimal) — fixes round-4's 1.15e7 conflicts.
// Q is pre-scaled by 0.125 in k_gemm_qkv.
// MFMA 16x16x32_bf16: A[m=lane&15][k=quad*8+j], B[k=quad*8+j][n=lane&15],
// C col=lane&15 (=n), row=quad*4+r (=m).
__global__ __launch_bounds__(256) void k_attn(
    const bf16* __restrict__ Q, const bf16* __restrict__ K,
    const bf16* __restrict__ V, bf16* __restrict__ ctx) {
  __shared__ __align__(16) bf16 Ks[64 * 64];      // 8192 B, gl16-staged
  __shared__ __align__(16) bf16 Vs[64 * 72];      // 9216 B, [dh][key]
  __shared__ __align__(16) bf16 Ps[4 * 16 * 72];  // 9216 B, per-wave P
  const int tid = threadIdx.x, lane = tid & 63, wave = tid >> 6;
  const int l15 = lane & 15, quad = lane >> 4;
  const int bh = blockIdx.y;
  const size_t base = (size_t)bh * Sc * DHc;
  const bf16* Qb = Q + base; const bf16* Kb = K + base; const bf16* Vb = V + base;
  const int q0 = blockIdx.x * 64 + wave * 16;
  bf16* Pw = Ps + wave * (16 * 72);

  short8 aq[2];
#pragma unroll
  for (int kk2 = 0; kk2 < 2; kk2++)
    aq[kk2] = *(const short8*)(Qb + (size_t)(q0 + l15) * 64 + kk2 * 32 + quad * 8);

  float m_i[4], l_i[4];
  floatx4 o[4];
#pragma unroll
  for (int r = 0; r < 4; r++) { m_i[r] = -__builtin_inff(); l_i[r] = 0.f; }
#pragma unroll
  for (int n4 = 0; n4 < 4; n4++)
#pragma unroll
    for (int r = 0; r < 4; r++) o[n4][r] = 0.f;

  const int ksrow = tid >> 3, ksg = tid & 7;  // K staging: row 0..31(+32), granule
  const int vkp = tid >> 3, vdg = tid & 7;    // V staging: key-pair 0..31, dh-group
  const int vsg = ((vkp >> 2) ^ vdg) & 7;     // V staging granule swizzle

  for (int kt = 0; kt < Sc / 64; kt++) {
    const int kb = kt * 64;
    __syncthreads();  // prev tile's reads done; safe to restage
    // K: async gl16, pre-swizzled source granule, linear LDS dest
#pragma unroll
    for (int it = 0; it < 2; it++) {
      int row = ksrow + it * 32;
      gl16(Kb + (size_t)(kb + row) * 64 + ((ksg ^ (row & 7)) << 3),
           Ks + (it * 256 + wave * 64) * 8);
    }
    // V transposed: each thread stages 8 dh x 2 keys as packed u32
    {
      ushort8 a0 = *(const ushort8*)(Vb + (size_t)(kb + 2 * vkp) * 64 + vdg * 8);
      ushort8 a1 = *(const ushort8*)(Vb + (size_t)(kb + 2 * vkp + 1) * 64 + vdg * 8);
#pragma unroll
      for (int j = 0; j < 8; j++) {
        int dh = vdg * 8 + j;
        int elem = dh * 72 + vsg * 8 + (vkp & 3) * 2;
        *(unsigned int*)(Vs + elem) = (unsigned int)a0[j] | ((unsigned int)a1[j] << 16);
      }
    }
    __syncthreads();  // publish K (vmcnt drain) + V
    // QK^T: 4 key tiles of 16 x 2 k-halves
    floatx4 sc[4];
#pragma unroll
    for (int ni = 0; ni < 4; ni++) {
#pragma unroll
      for (int r = 0; r < 4; r++) sc[ni][r] = 0.f;
      const int key = ni * 16 + l15;
#pragma unroll
      for (int kk2 = 0; kk2 < 2; kk2++) {
        short8 bk = *(const short8*)(Ks + key * 64 +
                                     (((kk2 * 4 + quad) ^ (key & 7)) << 3));
        sc[ni] = mfma_bf16(aq[kk2], bk, sc[ni]);
      }
    }
    // online softmax (scores already scaled via Q)
    float rmax[4];
#pragma unroll
    for (int r = 0; r < 4; r++)
      rmax[r] = fmaxf(fmaxf(sc[0][r], sc[1][r]), fmaxf(sc[2][r], sc[3][r]));
#pragma unroll
    for (int off = 1; off < 16; off <<= 1)
#pragma unroll
      for (int r = 0; r < 4; r++) rmax[r] = fmaxf(rmax[r], __shfl_xor(rmax[r], off));
    float alpha[4], rsum[4];
#pragma unroll
    for (int r = 0; r < 4; r++) {
      float nm = fmaxf(m_i[r], rmax[r]);
      alpha[r] = __expf(m_i[r] - nm);
      m_i[r] = nm;
    }
#pragma unroll
    for (int ni = 0; ni < 4; ni++)
#pragma unroll
      for (int r = 0; r < 4; r++) sc[ni][r] = __expf(sc[ni][r] - m_i[r]);
#pragma unroll
    for (int r = 0; r < 4; r++)
      rsum[r] = (sc[0][r] + sc[1][r]) + (sc[2][r] + sc[3][r]);
#pragma unroll
    for (int off = 1; off < 16; off <<= 1)
#pragma unroll
      for (int r = 0; r < 4; r++) rsum[r] += __shfl_xor(rsum[r], off);
#pragma unroll
    for (int r = 0; r < 4; r++) l_i[r] = l_i[r] * alpha[r] + rsum[r];
#pragma unroll
    for (int n4 = 0; n4 < 4; n4++)
#pragma unroll
      for (int r = 0; r < 4; r++) o[n4][r] *= alpha[r];
    // P (C layout: row=quad*4+r is q, col=l15+16*ni is key) -> LDS -> A layout
#pragma unroll
    for (int ni = 0; ni < 4; ni++)
#pragma unroll
      for (int r = 0; r < 4; r++)
        Pw[(quad * 4 + r) * 72 + ni * 16 + l15] = __float2bfloat16(sc[ni][r]);
    __syncthreads();
    // PV: K=64 keys = 2 mfma steps
#pragma unroll
    for (int kk = 0; kk < 2; kk++) {
      short8 ap = *(const short8*)(Pw + l15 * 72 + kk * 32 + quad * 8);
#pragma unroll
      for (int n4 = 0; n4 < 4; n4++) {
        int dh = n4 * 16 + l15;
        short8 bv = *(const short8*)(Vs + dh * 72 +
                                     ((((kk * 4 + quad) ^ (dh >> 3)) & 7) << 3));
        o[n4] = mfma_bf16(ap, bv, o[n4]);
      }
    }
  }
  const int b = bh >> 4, h = bh & 15;
#pragma unroll
  for (int n4 = 0; n4 < 4; n4++)
#pragma unroll
    for (int r = 0; r < 4; r++) {
      int s = q0 + quad * 4 + r;
      int d = h * 64 + n4 * 16 + l15;
      ctx[(size_t)(b * Sc + s) * Dc + d] = __float2bfloat16(o[n4][r] / l_i[r]);
    }
}

// ------------------------------- router (pure fp32) ------------------------
__global__ __launch_bounds__(256) void k_router(
    const float* __restrict__ xn2f, const float* __restrict__ wr,
    int* __restrict__ topi, float* __restrict__ topw,
    int* __restrict__ counts, float* __restrict__ sum_probs,
    float* __restrict__ sum_z2) {
  __shared__ float sp[8]; __shared__ float sz[1]; __shared__ int scnt[8];
  const int tid = threadIdx.x, wave = tid >> 6, lane = tid & 63;
  if (tid < 8) { sp[tid] = 0.f; scnt[tid] = 0; }
  if (tid == 0) sz[0] = 0.f;
  __syncthreads();
  const int t = blockIdx.x * 4 + wave;
  float a[8];
#pragma unroll
  for (int e = 0; e < 8; e++) a[e] = 0.f;
  const float* xr = xn2f + (size_t)t * Dc;
#pragma unroll 4
  for (int i = 0; i < 16; i++) {
    int d = lane + i * 64;
    float xv = xr[d];
    floatx4 wa = *(const floatx4*)(wr + d * 8);
    floatx4 wb = *(const floatx4*)(wr + d * 8 + 4);
#pragma unroll
    for (int e = 0; e < 4; e++) a[e] += xv * wa[e];
#pragma unroll
    for (int e = 0; e < 4; e++) a[e + 4] += xv * wb[e];
  }
#pragma unroll
  for (int off = 1; off < 64; off <<= 1)
#pragma unroll
    for (int e = 0; e < 8; e++) a[e] += __shfl_xor(a[e], off);
  float mx = a[0];
#pragma unroll
  for (int e = 1; e < 8; e++) mx = fmaxf(mx, a[e]);
  float pr[8], sum = 0.f;
#pragma unroll
  for (int e = 0; e < 8; e++) { pr[e] = __expf(a[e] - mx); sum += pr[e]; }
  float inv = 1.f / sum;
#pragma unroll
  for (int e = 0; e < 8; e++) pr[e] *= inv;
  float lse = mx + logf(sum);
  int i0 = 0; float p0 = pr[0];
#pragma unroll
  for (int e = 1; e < 8; e++) if (pr[e] > p0) { p0 = pr[e]; i0 = e; }
  int i1 = -1; float p1 = -1.f;
#pragma unroll
  for (int e = 0; e < 8; e++) if (e != i0 && pr[e] > p1) { p1 = pr[e]; i1 = e; }
  float wsum = p0 + p1;
  if (lane == 0) {
    topi[2 * t] = i0; topi[2 * t + 1] = i1;
    topw[2 * t] = p0 / wsum; topw[2 * t + 1] = p1 / wsum;
    atomicAdd(&scnt[i0], 1); atomicAdd(&scnt[i1], 1);
#pragma unroll
    for (int e = 0; e < 8; e++) atomicAdd(&sp[e], pr[e]);
    atomicAdd(&sz[0], lse * lse);
  }
  __syncthreads();
  if (tid < 8) { atomicAdd(&counts[tid], scnt[tid]); atomicAdd(&sum_probs[tid], sp[tid]); }
  if (tid == 0) atomicAdd(sum_z2, sz[0]);
}

// offsets + router loss (single thread)
__global__ void k_meta(const int* __restrict__ counts, int* __restrict__ offs,
                       const float* __restrict__ sum_probs,
                       const float* __restrict__ sum_z2, float* __restrict__ loss_out) {
  float aux = 0.f;
  offs[0] = 0;
  for (int e = 0; e < 8; e++) {
    offs[e + 1] = offs[e] + counts[e];
    aux += ((float)counts[e] / Tc) * (sum_probs[e] / Tc);
  }
  float loss = (float)Ec * aux * 0.5f + 0.001f * (sum_z2[0] / Tc);
  loss_out[0] = loss;
}

// gather tokens into per-expert segments; record row slots for combine
__global__ __launch_bounds__(256) void k_gather(
    const bf16* __restrict__ xn2, const int* __restrict__ topi,
    const int* __restrict__ offs, int* __restrict__ cursors,
    int* __restrict__ rowpos, bf16* __restrict__ Ag) {
  const int tid = threadIdx.x, wave = tid >> 6, lane = tid & 63;
  const int t = blockIdx.x * 4 + wave;
  const int i0 = topi[2 * t], i1 = topi[2 * t + 1];
  int r0 = 0, r1 = 0;
  if (lane == 0) {
    r0 = atomicAdd(&cursors[i0], 1);
    r1 = atomicAdd(&cursors[i1], 1);
    rowpos[2 * t] = r0; rowpos[2 * t + 1] = r1;
  }
  r0 = __shfl(r0, 0); r1 = __shfl(r1, 0);
  const short8* src = (const short8*)(xn2 + (size_t)t * Dc);
  short8 c0 = src[lane], c1 = src[lane + 64];
  short8* d0 = (short8*)(Ag + (size_t)(offs[i0] + r0) * Dc);
  short8* d1 = (short8*)(Ag + (size_t)(offs[i1] + r1) * Dc);
  d0[lane] = c0; d0[lane + 64] = c1;
  d1[lane] = c0; d1[lane + 64] = c1;
}

// ------------------------------ expert FFN ---------------------------------
// Natural block mapping (no XCD swizzle): with early-exit on by*128 >= cnt,
// the XCD swizzle concentrated valid blocks on XCDs {0,1} (rounds 2/3).
__global__ __launch_bounds__(256, 4) void k_ffn1(
    const bf16* __restrict__ Ag, const bf16* __restrict__ w1t,
    bf16* __restrict__ Hb, const int* __restrict__ offs) {
  const int e = blockIdx.z;
  const int cnt = offs[e + 1] - offs[e];
  const int m0 = blockIdx.y * 128;
  if (m0 >= cnt) return;
  GEMM_SHARED; LANE_DECODE;
  const int n0 = blockIdx.x * 128;
  const bf16* A = Ag + (size_t)offs[e] * Dc;
  const bf16* W = w1t + (size_t)e * Dc * Fc;  // [Fc][Dc]
  bf16* Hp = Hb + (size_t)offs[e] * Fc;
  floatx4 acc[4][4];
  gemm_core(As, Bs, A, Dc, m0, W, Dc, n0, Dc, acc);
#pragma unroll
  for (int mi = 0; mi < 4; mi++)
#pragma unroll
    for (int ni = 0; ni < 4; ni++)
#pragma unroll
      for (int r = 0; r < 4; r++) {
        int row = m0 + wm * 64 + mi * 16 + quad * 4 + r;
        int col = n0 + wn * 64 + ni * 16 + l15;
        if (row < cnt)
          Hp[(size_t)row * Fc + col] = __float2bfloat16(gelu_tanh(acc[mi][ni][r]));
      }
}

__global__ __launch_bounds__(256, 4) void k_ffn2(
    const bf16* __restrict__ Hb, const bf16* __restrict__ w2t,
    float* __restrict__ Ob, const int* __restrict__ offs) {
  const int e = blockIdx.z;
  const int cnt = offs[e + 1] - offs[e];
  const int m0 = blockIdx.y * 128;
  if (m0 >= cnt) return;
  GEMM_SHARED; LANE_DECODE;
  const int n0 = blockIdx.x * 128;
  const bf16* A = Hb + (size_t)offs[e] * Fc;
  const bf16* W = w2t + (size_t)e * Fc * Dc;  // [Dc][Fc]
  float* Op = Ob + (size_t)offs[e] * Dc;
  floatx4 acc[4][4];
  gemm_core(As, Bs, A, Fc, m0, W, Fc, n0, Fc, acc);
#pragma unroll
  for (int mi = 0; mi < 4; mi++)
#pragma unroll
    for (int ni = 0; ni < 4; ni++)
#pragma unroll
      for (int r = 0; r < 4; r++) {
        int row = m0 + wm * 64 + mi * 16 + quad * 4 + r;
        int col = n0 + wn * 64 + ni * 16 + l15;
        if (row < cnt) Op[(size_t)row * Dc + col] = acc[mi][ni][r];
      }
}

// ------------------------------- combine -----------------------------------
__global__ __launch_bounds__(256) void k_combine(
    const float* __restrict__ x1, const float* __restrict__ Ob,
    const int* __restrict__ topi, const float* __restrict__ topw,
    const int* __restrict__ rowpos, const int* __restrict__ offs,
    float* __restrict__ out) {
  const int t = blockIdx.x, tid = threadIdx.x;
  const int i0 = topi[2 * t], i1 = topi[2 * t + 1];
  const float w0 = topw[2 * t], w1 = topw[2 * t + 1];
  const float* o0 = Ob + (size_t)(offs[i0] + rowpos[2 * t]) * Dc;
  const float* o1 = Ob + (size_t)(offs[i1] + rowpos[2 * t + 1]) * Dc;
  const float* xr = x1 + (size_t)t * Dc;
  floatx4 a = *(const floatx4*)(xr + tid * 4);
  floatx4 b = *(const floatx4*)(o0 + tid * 4);
  floatx4 c = *(const floatx4*)(o1 + tid * 4);
  floatx4 res;
#pragma unroll
  for (int j = 0; j < 4; j++) res[j] = a[j] + w0 * b[j] + w1 * c[j];
  *(floatx4*)(out + (size_t)t * Dc + tid * 4) = res;
}

// ---------------------------------------------------------------------------
extern "C" void kernel_launch(void* const* d_in, const int* in_sizes, int n_in,
                              void* d_out, int out_size, void* d_ws, size_t ws_size,
                              hipStream_t stream) {
  (void)in_sizes; (void)n_in; (void)out_size; (void)ws_size;
  const float* x    = (const float*)d_in[0];
  const float* ln1w = (const float*)d_in[1];
  const float* ln2w = (const float*)d_in[2];
  const float* wq   = (const float*)d_in[3];
  const float* wk   = (const float*)d_in[4];
  const float* wv   = (const float*)d_in[5];
  const float* wo   = (const float*)d_in[6];
  const float* wr   = (const float*)d_in[7];
  const float* w1   = (const float*)d_in[8];
  const float* w2   = (const float*)d_in[9];
  float* out = (float*)d_out;

  char* p = (char*)d_ws;
  auto take = [&](size_t bytes) {
    char* r = p; p += (bytes + 255) & ~(size_t)255; return r;
  };
  bf16*  xn   = (bf16*)take((size_t)Tc * Dc * 2);
  bf16*  qb   = (bf16*)take((size_t)Tc * Dc * 2);
  bf16*  kb   = (bf16*)take((size_t)Tc * Dc * 2);
  bf16*  vb   = (bf16*)take((size_t)Tc * Dc * 2);
  bf16*  ctx  = (bf16*)take((size_t)Tc * Dc * 2);
  float* x1   = (float*)take((size_t)Tc * Dc * 4);
  bf16*  xn2  = (bf16*)take((size_t)Tc * Dc * 2);
  float* xn2f = (float*)take((size_t)Tc * Dc * 4);
  bf16*  Ag   = (bf16*)take((size_t)2 * Tc * Dc * 2);
  bf16*  Hb   = (bf16*)take((size_t)2 * Tc * Fc * 2);
  float* Ob   = (float*)take((size_t)2 * Tc * Dc * 4);
  bf16*  wtqkvo = (bf16*)take((size_t)4 * Dc * Dc * 2);           // q,k,v,o transposed bf16
  bf16*  wtbig  = (bf16*)take((size_t)Ec * (size_t)Dc * Fc * 2);  // shared w1t, then w2t
  int*   counts    = (int*)take(512);      // [0:8) counts, then cursors, sums
  int*   cursors   = counts + 8;
  float* sum_probs = (float*)(counts + 16);
  float* sum_z2    = sum_probs + 8;
  int*   offs      = (int*)take(256);
  int*   topi      = (int*)take((size_t)2 * Tc * 4);
  float* topw      = (float*)take((size_t)2 * Tc * 4);
  int*   rowpos    = (int*)take((size_t)2 * Tc * 4);

  hipMemsetAsync(counts, 0, 512, stream);

  // weight conversion (transpose fp32 [K][N] -> bf16 [N][K])
  k_wt4<<<dim3(Dc / 64, Dc / 64, 4), 256, 0, stream>>>(wq, wk, wv, wo, wtqkvo);
  k_wt<<<dim3(Fc / 64, Dc / 64, Ec), 256, 0, stream>>>(w1, wtbig, Dc, Fc);

  k_rms<<<Tc, 256, 0, stream>>>(x, ln1w, xn, nullptr);
  k_gemm_qkv<<<dim3(Dc / 128, Tc / 128, 3), 256, 0, stream>>>(xn, wtqkvo, qb, kb, vb);
  k_attn<<<dim3(Sc / 64, Bc * Hc), 256, 0, stream>>>(qb, kb, vb, ctx);
  k_gemm_wo<<<dim3(Dc / 128, Tc / 128), 256, 0, stream>>>(ctx, wtqkvo + (size_t)3 * Dc * Dc, x, x1);
  k_rms<<<Tc, 256, 0, stream>>>(x1, ln2w, xn2, xn2f);
  k_router<<<Tc / 4, 256, 0, stream>>>(xn2f, wr, topi, topw, counts, sum_probs, sum_z2);
  k_meta<<<1, 1, 0, stream>>>(counts, offs, sum_probs, sum_z2, out + (size_t)Tc * Dc);
  k_gather<<<Tc / 4, 256, 0, stream>>>(xn2, topi, offs, cursors, rowpos, Ag);
  k_ffn1<<<dim3(Fc / 128, Tc / 128, Ec), 256, 0, stream>>>(Ag, wtbig, Hb, offs);
  // w2 conversion reuses wtbig (stream-ordered after ffn1)
  k_wt<<<dim3(Dc / 64, Fc / 64, Ec), 256, 0, stream>>>(w2, wtbig, Fc, Dc);
  k_ffn2<<<dim3(Dc / 128, Tc / 128, Ec), 256, 0, stream>>>(Hb, wtbig, Ob, offs);
  k_combine<<<Tc, 256, 0, stream>>>(x1, Ob, topi, topw, rowpos, offs, out);
}